// Round 2
// baseline (1053.596 us; speedup 1.0000x reference)
//
#include <hip/hip_runtime.h>
#include <hip/hip_bf16.h>
#include <math.h>

// Problem dims (fixed by setup_inputs): B=16,S=512,W=5,D=200,H=768
// Restructured math (softmax shift-invariance + linearity):
//   C = attn_W @ W2^T                  [768,768]   (precomputed per call, cheap)
//   T = tanh(E @ W1 + b1)              [40960,768] (stored bf16)
//   P = x @ C                          [8192,768]
//   logits_w = T_w . P   (the q.b2 term is constant across w -> dropped)
//   alpha = softmax(logits + mask_bias)
//   S = sum_w alpha_w T_w              [8192,768]  (stored bf16)
//   H = x + S @ W2 + b2                [8192,768]
//   out = LayerNorm(H) * gamma + beta
//
// R2 fix: word_mask arrives as int32 (harness converts integer inputs to
// int32), NOT int64 — reading it as long long produced garbage logit biases.

// ---------------- 128x128 fp32 GEMM, 8x8 micro-tile ----------------
template<bool A_BF16, bool HAS_BIAS, bool TANH_ACT, bool RESID, bool OUT_BF16>
__global__ __launch_bounds__(256) void gemm128(
    const void* __restrict__ Aptr, const float* __restrict__ Bptr,
    const float* __restrict__ bias, const float* __restrict__ resid,
    void* __restrict__ outptr, int M, int N, int K)
{
    __shared__ float As[16][132];   // [k][m]
    __shared__ float Bs[16][132];   // [k][n]
    const int tid = threadIdx.x;
    const int tx = tid & 15;        // n micro index
    const int ty = tid >> 4;        // m micro index
    const int n0 = blockIdx.x * 128;
    const int m0 = blockIdx.y * 128;

    float acc[8][8];
#pragma unroll
    for (int i = 0; i < 8; i++)
#pragma unroll
        for (int j = 0; j < 8; j++) acc[i][j] = 0.f;

    for (int k0 = 0; k0 < K; k0 += 16) {
        // stage A tile: A[m0+m][k0+ka], m = (tid>>4)*8+i, ka = tid&15
#pragma unroll
        for (int i = 0; i < 8; i++) {
            int m = (tid >> 4) * 8 + i;
            int k = k0 + (tid & 15);
            float v = 0.f;
            if (k < K) {
                if (A_BF16) v = __bfloat162float(((const __hip_bfloat16*)Aptr)[(size_t)(m0 + m) * K + k]);
                else        v = ((const float*)Aptr)[(size_t)(m0 + m) * K + k];
            }
            As[tid & 15][m] = v;
        }
        // stage B tile: B[k0+kk][n0+n], kk = (tid>>7)+2*i, n = tid&127
#pragma unroll
        for (int i = 0; i < 8; i++) {
            int kk = (tid >> 7) + 2 * i;
            int n  = tid & 127;
            int k  = k0 + kk;
            Bs[kk][n] = (k < K) ? Bptr[(size_t)k * N + n0 + n] : 0.f;
        }
        __syncthreads();
#pragma unroll
        for (int kk = 0; kk < 16; kk++) {
            float4 a0 = *(const float4*)&As[kk][ty * 8];
            float4 a1 = *(const float4*)&As[kk][ty * 8 + 4];
            float4 b0 = *(const float4*)&Bs[kk][tx * 8];
            float4 b1 = *(const float4*)&Bs[kk][tx * 8 + 4];
            float a[8] = {a0.x, a0.y, a0.z, a0.w, a1.x, a1.y, a1.z, a1.w};
            float b[8] = {b0.x, b0.y, b0.z, b0.w, b1.x, b1.y, b1.z, b1.w};
#pragma unroll
            for (int i = 0; i < 8; i++)
#pragma unroll
                for (int j = 0; j < 8; j++)
                    acc[i][j] = fmaf(a[i], b[j], acc[i][j]);
        }
        __syncthreads();
    }

    // epilogue
#pragma unroll
    for (int i = 0; i < 8; i++) {
        int row = m0 + ty * 8 + i;
        float vals[8];
#pragma unroll
        for (int j = 0; j < 8; j++) {
            int col = n0 + tx * 8 + j;
            float v = acc[i][j];
            if (HAS_BIAS) v += bias[col];
            if (TANH_ACT) v = tanhf(v);
            if (RESID)    v += resid[(size_t)row * N + col];
            vals[j] = v;
        }
        if (OUT_BF16) {
            alignas(16) __hip_bfloat16 h8[8];
#pragma unroll
            for (int j = 0; j < 8; j++) h8[j] = __float2bfloat16(vals[j]);
            __hip_bfloat16* o = (__hip_bfloat16*)outptr + (size_t)row * N + n0 + tx * 8;
            *(uint4*)o = *(const uint4*)h8;
        } else {
            float* o = (float*)outptr + (size_t)row * N + n0 + tx * 8;
            *(float4*)(o)     = make_float4(vals[0], vals[1], vals[2], vals[3]);
            *(float4*)(o + 4) = make_float4(vals[4], vals[5], vals[6], vals[7]);
        }
    }
}

// ---------------- 768x768 transpose (W2 -> W2^T) ----------------
__global__ __launch_bounds__(256) void transpose768(const float* __restrict__ in,
                                                    float* __restrict__ out)
{
    __shared__ float tile[32][33];
    const int bx = blockIdx.x * 32, by = blockIdx.y * 32;
    const int x = threadIdx.x, y = threadIdx.y;     // block (32,8)
#pragma unroll
    for (int i = 0; i < 32; i += 8)
        tile[y + i][x] = in[(size_t)(by + y + i) * 768 + bx + x];
    __syncthreads();
#pragma unroll
    for (int i = 0; i < 32; i += 8)
        out[(size_t)(bx + y + i) * 768 + by + x] = tile[x][y + i];
}

// ---------------- attention: logits, softmax over 5 words, weighted sum ----------------
__global__ __launch_bounds__(256) void attn_kernel(
    const __hip_bfloat16* __restrict__ T,   // [8192*5, 768]
    const float* __restrict__ P,            // [8192, 768]
    const int* __restrict__ mask,           // [8192, 5] int32 (harness-converted)
    __hip_bfloat16* __restrict__ S)         // [8192, 768]
{
    const int r = blockIdx.x;               // (b,s) row 0..8191
    const int t = threadIdx.x;              // 0..255
    __shared__ float red[5][256];
    __shared__ float alpha_sh[5];

    float pv[3], tv[5][3];
    float part[5] = {0.f, 0.f, 0.f, 0.f, 0.f};
#pragma unroll
    for (int c = 0; c < 3; c++) pv[c] = P[(size_t)r * 768 + t + 256 * c];
#pragma unroll
    for (int w = 0; w < 5; w++) {
        const __hip_bfloat16* Trow = T + ((size_t)r * 5 + w) * 768;
#pragma unroll
        for (int c = 0; c < 3; c++) {
            float v = __bfloat162float(Trow[t + 256 * c]);
            tv[w][c] = v;
            part[w] += v * pv[c];
        }
    }
#pragma unroll
    for (int w = 0; w < 5; w++) red[w][t] = part[w];
    __syncthreads();
    for (int off = 128; off > 0; off >>= 1) {
        if (t < off) {
#pragma unroll
            for (int w = 0; w < 5; w++) red[w][t] += red[w][t + off];
        }
        __syncthreads();
    }
    if (t == 0) {
        float logit[5], mx = -1e30f;
#pragma unroll
        for (int w = 0; w < 5; w++) {
            float m = (float)mask[(size_t)r * 5 + w];
            logit[w] = red[w][0] + (1.0f - m) * (-10000.0f);
            mx = fmaxf(mx, logit[w]);
        }
        float se = 0.f;
#pragma unroll
        for (int w = 0; w < 5; w++) { logit[w] = expf(logit[w] - mx); se += logit[w]; }
        float inv = 1.0f / se;
#pragma unroll
        for (int w = 0; w < 5; w++) alpha_sh[w] = logit[w] * inv;
    }
    __syncthreads();
    float a[5];
#pragma unroll
    for (int w = 0; w < 5; w++) a[w] = alpha_sh[w];
#pragma unroll
    for (int c = 0; c < 3; c++) {
        float s = 0.f;
#pragma unroll
        for (int w = 0; w < 5; w++) s += a[w] * tv[w][c];
        S[(size_t)r * 768 + t + 256 * c] = __float2bfloat16(s);
    }
}

// ---------------- LayerNorm over H=768 ----------------
__global__ __launch_bounds__(256) void ln_kernel(
    const float* __restrict__ Hbuf, const float* __restrict__ gamma,
    const float* __restrict__ beta, float* __restrict__ out)
{
    const int r = blockIdx.x, t = threadIdx.x;
    __shared__ float red[256];
    float v[3];
    float s = 0.f;
#pragma unroll
    for (int c = 0; c < 3; c++) { v[c] = Hbuf[(size_t)r * 768 + t + 256 * c]; s += v[c]; }
    red[t] = s; __syncthreads();
    for (int off = 128; off > 0; off >>= 1) { if (t < off) red[t] += red[t + off]; __syncthreads(); }
    const float mu = red[0] * (1.f / 768.f);
    __syncthreads();
    float vs = 0.f;
#pragma unroll
    for (int c = 0; c < 3; c++) { float d = v[c] - mu; vs += d * d; }
    red[t] = vs; __syncthreads();
    for (int off = 128; off > 0; off >>= 1) { if (t < off) red[t] += red[t + off]; __syncthreads(); }
    const float var = red[0] * (1.f / 768.f);
    const float rs = rsqrtf(var + 1e-12f);
#pragma unroll
    for (int c = 0; c < 3; c++) {
        int h = t + 256 * c;
        out[(size_t)r * 768 + h] = (v[c] - mu) * rs * gamma[h] + beta[h];
    }
}

extern "C" void kernel_launch(void* const* d_in, const int* in_sizes, int n_in,
                              void* d_out, int out_size, void* d_ws, size_t ws_size,
                              hipStream_t stream)
{
    const float* x      = (const float*)d_in[0];      // [8192,768]
    const float* E      = (const float*)d_in[1];      // [40960,200]
    const int*   mask   = (const int*)d_in[2];        // [8192,5] int32
    const float* W1     = (const float*)d_in[3];      // [200,768]
    const float* b1     = (const float*)d_in[4];      // [768]
    const float* W2     = (const float*)d_in[5];      // [768,768]
    const float* b2     = (const float*)d_in[6];      // [768]
    const float* attn_W = (const float*)d_in[7];      // [768,768]
    const float* gamma  = (const float*)d_in[8];      // [768]
    const float* beta   = (const float*)d_in[9];      // [768]
    float* out = (float*)d_out;

    const int BS = 16 * 512;        // 8192 (b,s) rows
    const int NW = 5;
    const int D  = 200;
    const int H  = 768;
    const int M1 = BS * NW;         // 40960

    // workspace carve-up
    char* p = (char*)d_ws;
    float* W2T = (float*)p;            p += (size_t)H * H * 4;    //  2.36 MB
    float* Cm  = (float*)p;            p += (size_t)H * H * 4;    //  2.36 MB
    __hip_bfloat16* T = (__hip_bfloat16*)p; p += (size_t)M1 * H * 2;  // 62.9 MB
    float* P   = (float*)p;            p += (size_t)BS * H * 4;   // 25.2 MB
    __hip_bfloat16* S = (__hip_bfloat16*)p; p += (size_t)BS * H * 2;  // 12.6 MB
    // Hbuf aliases T's region: T dead after attn_kernel; agg GEMM reads only S,x,W2
    float* Hb  = (float*)T;

    // 1) W2T = W2^T
    transpose768<<<dim3(24, 24), dim3(32, 8), 0, stream>>>(W2, W2T);
    // 2) C = attn_W @ W2^T   [768,768]
    gemm128<false, false, false, false, false><<<dim3(6, 6), 256, 0, stream>>>(
        attn_W, W2T, nullptr, nullptr, Cm, H, H, H);
    // 3) T = tanh(E @ W1 + b1)   [40960,768] bf16
    gemm128<false, true, true, false, true><<<dim3(6, 320), 256, 0, stream>>>(
        E, W1, b1, nullptr, T, M1, H, D);
    // 4) P = x @ C   [8192,768]
    gemm128<false, false, false, false, false><<<dim3(6, 64), 256, 0, stream>>>(
        x, Cm, nullptr, nullptr, P, BS, H, H);
    // 5) attention -> S  [8192,768] bf16
    attn_kernel<<<BS, 256, 0, stream>>>(T, P, mask, S);
    // 6) Hb = x + S @ W2 + b2   [8192,768]
    gemm128<true, true, false, true, false><<<dim3(6, 64), 256, 0, stream>>>(
        S, W2, b2, x, Hb, BS, H, H);
    // 7) out = LN(Hb)*gamma + beta
    ln_kernel<<<BS, 256, 0, stream>>>(Hb, gamma, beta, out);
}

// Round 3
// 285.833 us; speedup vs baseline: 3.6861x; 3.6861x over previous
//
#include <hip/hip_runtime.h>
#include <hip/hip_bf16.h>
#include <math.h>

// Problem dims: B=16,S=512,W=5,D=200,H=768  (BS=8192 rows, M1=40960 word-rows)
// Restructured math (softmax shift-invariance + linearity):
//   Ct = W2 @ attn_W^T                [768,768] bf16  (B^T operand for P-GEMM)
//   T  = tanh(E @ W1 + b1)            [40960,768] bf16   (K padded 200->256)
//   P  = x @ C                        [8192,768] bf16    (logit_w = T_w . P)
//   alpha = softmax(logits + mask_bias); S = sum_w alpha_w T_w   [8192,768] bf16
//   H  = x + S @ W2 + b2              [8192,768] fp32
//   out = LayerNorm(H) * gamma + beta
// All GEMMs: MFMA bf16 16x16x32, 128x128 tile, BK=32, global_load_lds staging.

typedef __attribute__((ext_vector_type(8))) short bf16x8;
typedef __attribute__((ext_vector_type(4))) float f32x4;

__device__ __forceinline__ unsigned short f2bf_bits(float f) {
    __hip_bfloat16 h = __float2bfloat16(f);
    return *reinterpret_cast<unsigned short*>(&h);
}
__device__ __forceinline__ float bf_bits2f(unsigned short u) {
    union { unsigned int i; float f; } v; v.i = ((unsigned int)u) << 16; return v.f;
}

// async 16B/lane global->LDS (wave-uniform chunk base + lane*16 layout)
__device__ __forceinline__ void async_cp16(const void* g, void* lds) {
#if __has_builtin(__builtin_amdgcn_global_load_lds)
    auto gp = (const __attribute__((address_space(1))) unsigned int*)g;
    auto lp = (__attribute__((address_space(3))) unsigned int*)lds;
    __builtin_amdgcn_global_load_lds(gp, lp, 16, 0, 0);
#else
    *(uint4*)lds = *(const uint4*)g;   // fallback: register round-trip
#endif
}

// ---------- MFMA bf16 GEMM: D = A[M,K] @ Bt[N,K]^T (+bias)(tanh)(+resid) ----------
// requires M%128==0, N%128==0, K%32==0, K%8==0 (16B-aligned rows)
template<bool HAS_BIAS, bool TANH_ACT, bool RESID, bool OUT_BF16>
__global__ __launch_bounds__(256) void mfma_gemm(
    const __hip_bfloat16* __restrict__ A,
    const __hip_bfloat16* __restrict__ Bt,
    const float* __restrict__ bias,
    const float* __restrict__ resid,
    void* __restrict__ outp,
    int M, int N, int K)
{
    __shared__ __align__(16) unsigned short As[128 * 32];   // [row][k] 64B rows
    __shared__ __align__(16) unsigned short Bs[128 * 32];
    const int tid  = threadIdx.x;
    const int lane = tid & 63;
    const int wave = tid >> 6;          // 4 waves in 2x2
    const int wm   = wave & 1;
    const int wn   = wave >> 1;
    const int m0   = blockIdx.y * 128;
    const int n0   = blockIdx.x * 128;

    // staging: wave handles chunks {2w, 2w+1} of A and B; chunk = 16 rows x 32 k
    const int srow  = lane >> 2;         // 0..15
    const int skoff = (lane & 3) * 8;    // k element offset 0/8/16/24
    const __hip_bfloat16* gA = A  + (size_t)(m0 + wave * 32 + srow) * K + skoff;
    const __hip_bfloat16* gB = Bt + (size_t)(n0 + wave * 32 + srow) * K + skoff;
    unsigned short* lA = &As[wave * 1024 + lane * 8];
    unsigned short* lB = &Bs[wave * 1024 + lane * 8];

    const int row16 = lane & 15;
    const int kq    = lane >> 4;         // 0..3

    f32x4 acc[4][4];
#pragma unroll
    for (int i = 0; i < 4; i++)
#pragma unroll
        for (int j = 0; j < 4; j++) acc[i][j] = (f32x4){0.f, 0.f, 0.f, 0.f};

    for (int k0 = 0; k0 < K; k0 += 32) {
        async_cp16(gA,          lA);
        async_cp16(gA + 16 * K, lA + 512);
        async_cp16(gB,          lB);
        async_cp16(gB + 16 * K, lB + 512);
        gA += 32; gB += 32;
        __syncthreads();                 // drains vmcnt before ds_read

        bf16x8 af[4], bg[4];
#pragma unroll
        for (int mi = 0; mi < 4; mi++)
            af[mi] = *(const bf16x8*)&As[(wm * 64 + mi * 16 + row16) * 32 + kq * 8];
#pragma unroll
        for (int ni = 0; ni < 4; ni++)
            bg[ni] = *(const bf16x8*)&Bs[(wn * 64 + ni * 16 + row16) * 32 + kq * 8];
#pragma unroll
        for (int mi = 0; mi < 4; mi++)
#pragma unroll
            for (int ni = 0; ni < 4; ni++)
                acc[mi][ni] = __builtin_amdgcn_mfma_f32_16x16x32_bf16(
                    af[mi], bg[ni], acc[mi][ni], 0, 0, 0);
        __syncthreads();
    }

    // epilogue: C/D layout col=lane&15, row=(lane>>4)*4+reg
#pragma unroll
    for (int mi = 0; mi < 4; mi++) {
#pragma unroll
        for (int ni = 0; ni < 4; ni++) {
            const int gcol = n0 + wn * 64 + ni * 16 + row16;
            float bcol = 0.f;
            if (HAS_BIAS) bcol = bias[gcol];
#pragma unroll
            for (int r = 0; r < 4; r++) {
                const int grow = m0 + wm * 64 + mi * 16 + kq * 4 + r;
                float v = acc[mi][ni][r];
                if (HAS_BIAS) v += bcol;
                if (TANH_ACT) v = tanhf(v);
                if (RESID)    v += resid[(size_t)grow * N + gcol];
                if (OUT_BF16) ((__hip_bfloat16*)outp)[(size_t)grow * N + gcol] = __float2bfloat16(v);
                else          ((float*)outp)[(size_t)grow * N + gcol] = v;
            }
        }
    }
}

// ---------- fp32 -> bf16 elementwise (x4 vectorized), n must be %4 ----------
__global__ __launch_bounds__(256) void cvt_bf16x4(const float* __restrict__ in,
                                                  __hip_bfloat16* __restrict__ out,
                                                  long long n4)
{
    long long i = (long long)blockIdx.x * 256 + threadIdx.x;
    if (i < n4) {
        float4 v = ((const float4*)in)[i];
        ushort4 o = make_ushort4(f2bf_bits(v.x), f2bf_bits(v.y), f2bf_bits(v.z), f2bf_bits(v.w));
        ((ushort4*)out)[i] = o;
    }
}

// ---------- E [40960,200] fp32 -> Eb [40960,256] bf16 (zero-padded K) ----------
__global__ __launch_bounds__(256) void cvt_padE(const float* __restrict__ E,
                                                __hip_bfloat16* __restrict__ Eb)
{
    const int row = blockIdx.x, k = threadIdx.x;
    float v = (k < 200) ? E[(size_t)row * 200 + k] : 0.f;
    Eb[(size_t)row * 256 + k] = __float2bfloat16(v);
}

// ---------- transpose+cvt: in[R,C] fp32 -> out[C,Rpad] bf16 (rows R..Rpad zero) ----------
__global__ __launch_bounds__(256) void transpose_cvt(const float* __restrict__ in,
                                                     __hip_bfloat16* __restrict__ out,
                                                     int R, int C, int Rpad)
{
    __shared__ float tile[32][33];
    const int c0 = blockIdx.x * 32, r0 = blockIdx.y * 32;
    const int x = threadIdx.x, y = threadIdx.y;     // block (32,8)
#pragma unroll
    for (int i = 0; i < 32; i += 8) {
        int r = r0 + y + i;
        tile[y + i][x] = (r < R) ? in[(size_t)r * C + c0 + x] : 0.f;
    }
    __syncthreads();
#pragma unroll
    for (int i = 0; i < 32; i += 8)
        out[(size_t)(c0 + y + i) * Rpad + r0 + x] = __float2bfloat16(tile[x][y + i]);
}

// ---------- attention: wave per (b,s) row; P may alias S ----------
__global__ __launch_bounds__(256) void attn_kernel(
    const __hip_bfloat16* __restrict__ T,   // [40960,768]
    const __hip_bfloat16* P,                // [8192,768]  (aliases S)
    const int* __restrict__ mask,           // [8192,5] int32
    __hip_bfloat16* S)                      // [8192,768]
{
    const int lane = threadIdx.x & 63;
    const int wave = threadIdx.x >> 6;
    const int r    = blockIdx.x * 4 + wave;
    const int base = lane * 12;             // 12 elems per lane, 64*12=768

    float pv[12];
    {
        const ushort4* pp = (const ushort4*)((const unsigned short*)P + (size_t)r * 768 + base);
        ushort4 u0 = pp[0], u1 = pp[1], u2 = pp[2];
        unsigned short us[12] = {u0.x,u0.y,u0.z,u0.w, u1.x,u1.y,u1.z,u1.w, u2.x,u2.y,u2.z,u2.w};
#pragma unroll
        for (int j = 0; j < 12; j++) pv[j] = bf_bits2f(us[j]);
    }
    float tv[5][12], part[5];
#pragma unroll
    for (int w = 0; w < 5; w++) {
        const ushort4* tp = (const ushort4*)((const unsigned short*)T + ((size_t)r * 5 + w) * 768 + base);
        ushort4 u0 = tp[0], u1 = tp[1], u2 = tp[2];
        unsigned short us[12] = {u0.x,u0.y,u0.z,u0.w, u1.x,u1.y,u1.z,u1.w, u2.x,u2.y,u2.z,u2.w};
        float s = 0.f;
#pragma unroll
        for (int j = 0; j < 12; j++) { tv[w][j] = bf_bits2f(us[j]); s += tv[w][j] * pv[j]; }
        part[w] = s;
    }
#pragma unroll
    for (int off = 32; off > 0; off >>= 1)
#pragma unroll
        for (int w = 0; w < 5; w++)
            part[w] += __shfl_xor(part[w], off, 64);

    float logit[5], mx = -1e30f;
#pragma unroll
    for (int w = 0; w < 5; w++) {
        float m = (float)mask[(size_t)r * 5 + w];
        logit[w] = part[w] - 10000.0f * (1.0f - m);
        mx = fmaxf(mx, logit[w]);
    }
    float se = 0.f;
#pragma unroll
    for (int w = 0; w < 5; w++) { logit[w] = expf(logit[w] - mx); se += logit[w]; }
    const float inv = 1.0f / se;

    unsigned short os[12];
#pragma unroll
    for (int j = 0; j < 12; j++) {
        float s = 0.f;
#pragma unroll
        for (int w = 0; w < 5; w++) s += logit[w] * tv[w][j];
        os[j] = f2bf_bits(s * inv);
    }
    ushort4* sp = (ushort4*)((unsigned short*)S + (size_t)r * 768 + base);
    sp[0] = make_ushort4(os[0], os[1], os[2],  os[3]);
    sp[1] = make_ushort4(os[4], os[5], os[6],  os[7]);
    sp[2] = make_ushort4(os[8], os[9], os[10], os[11]);
}

// ---------- LayerNorm over H=768 ----------
__global__ __launch_bounds__(256) void ln_kernel(
    const float* __restrict__ Hbuf, const float* __restrict__ gamma,
    const float* __restrict__ beta, float* __restrict__ out)
{
    const int r = blockIdx.x, t = threadIdx.x;
    __shared__ float red[256];
    float v[3];
    float s = 0.f;
#pragma unroll
    for (int c = 0; c < 3; c++) { v[c] = Hbuf[(size_t)r * 768 + t + 256 * c]; s += v[c]; }
    red[t] = s; __syncthreads();
    for (int off = 128; off > 0; off >>= 1) { if (t < off) red[t] += red[t + off]; __syncthreads(); }
    const float mu = red[0] * (1.f / 768.f);
    __syncthreads();
    float vs = 0.f;
#pragma unroll
    for (int c = 0; c < 3; c++) { float d = v[c] - mu; vs += d * d; }
    red[t] = vs; __syncthreads();
    for (int off = 128; off > 0; off >>= 1) { if (t < off) red[t] += red[t + off]; __syncthreads(); }
    const float var = red[0] * (1.f / 768.f);
    const float rs = rsqrtf(var + 1e-12f);
#pragma unroll
    for (int c = 0; c < 3; c++) {
        int h = t + 256 * c;
        out[(size_t)r * 768 + h] = (v[c] - mu) * rs * gamma[h] + beta[h];
    }
}

extern "C" void kernel_launch(void* const* d_in, const int* in_sizes, int n_in,
                              void* d_out, int out_size, void* d_ws, size_t ws_size,
                              hipStream_t stream)
{
    const float* x      = (const float*)d_in[0];      // [8192,768]
    const float* E      = (const float*)d_in[1];      // [40960,200]
    const int*   mask   = (const int*)d_in[2];        // [8192,5] int32
    const float* W1     = (const float*)d_in[3];      // [200,768]
    const float* b1     = (const float*)d_in[4];      // [768]
    const float* W2     = (const float*)d_in[5];      // [768,768]
    const float* b2     = (const float*)d_in[6];      // [768]
    const float* attn_W = (const float*)d_in[7];      // [768,768]
    const float* gamma  = (const float*)d_in[8];      // [768]
    const float* beta   = (const float*)d_in[9];      // [768]
    float* out = (float*)d_out;

    const int BS = 8192, H = 768, M1 = 40960;

    // workspace carve-up (<=102 MB; 105.4 MB was proven available in R2)
    char* p = (char*)d_ws;
    auto alloc = [&](size_t bytes) { char* q = p; p += (bytes + 255) & ~(size_t)255; return q; };
    __hip_bfloat16* xb    = (__hip_bfloat16*)alloc((size_t)BS * H * 2);   // 12.58 MB
    __hip_bfloat16* W2b   = (__hip_bfloat16*)alloc((size_t)H * H * 2);
    __hip_bfloat16* W2Tb  = (__hip_bfloat16*)alloc((size_t)H * H * 2);
    __hip_bfloat16* attnb = (__hip_bfloat16*)alloc((size_t)H * H * 2);
    __hip_bfloat16* Ctb   = (__hip_bfloat16*)alloc((size_t)H * H * 2);
    __hip_bfloat16* W1Tb  = (__hip_bfloat16*)alloc((size_t)H * 256 * 2);
    __hip_bfloat16* Tb    = (__hip_bfloat16*)alloc((size_t)M1 * H * 2);  // 62.91 MB
    __hip_bfloat16* Eb    = (__hip_bfloat16*)alloc((size_t)M1 * 256 * 2);// 20.97 MB
    float* Hb = (float*)Tb;              // alias: Tb dead after attn
    __hip_bfloat16* Pb = Eb;             // alias: Eb dead after T-GEMM
    __hip_bfloat16* Sb = Pb;             // alias: attn reads P row before writing S row (same wave)

    // --- conversions (independent) ---
    cvt_bf16x4<<<(BS * H / 4 + 255) / 256, 256, 0, stream>>>(x, xb, (long long)BS * H / 4);
    cvt_bf16x4<<<(H * H / 4 + 255) / 256, 256, 0, stream>>>(W2, W2b, (long long)H * H / 4);
    cvt_bf16x4<<<(H * H / 4 + 255) / 256, 256, 0, stream>>>(attn_W, attnb, (long long)H * H / 4);
    cvt_padE<<<M1, 256, 0, stream>>>(E, Eb);
    transpose_cvt<<<dim3(24, 8),  dim3(32, 8), 0, stream>>>(W1, W1Tb, 200, H, 256);
    transpose_cvt<<<dim3(24, 24), dim3(32, 8), 0, stream>>>(W2, W2Tb, H, H, H);

    // --- Ct = W2 @ attn_W^T  (row-major A=W2b, Bt=attnb) -> bf16 [768,768] ---
    mfma_gemm<false, false, false, true><<<dim3(6, 6), 256, 0, stream>>>(
        W2b, attnb, nullptr, nullptr, Ctb, H, H, H);
    // --- T = tanh(Eb @ W1 + b1) -> bf16 [40960,768], K=256 padded ---
    mfma_gemm<true, true, false, true><<<dim3(6, 320), 256, 0, stream>>>(
        Eb, W1Tb, b1, nullptr, Tb, M1, H, 256);
    // --- P = x @ C -> bf16 [8192,768] (into Eb region) ---
    mfma_gemm<false, false, false, true><<<dim3(6, 64), 256, 0, stream>>>(
        xb, Ctb, nullptr, nullptr, Pb, BS, H, H);
    // --- attention -> S bf16 (aliases P) ---
    attn_kernel<<<BS / 4, 256, 0, stream>>>(Tb, Pb, mask, Sb);
    // --- H = x + S @ W2 + b2 -> fp32 (into Tb region) ---
    mfma_gemm<true, false, true, false><<<dim3(6, 64), 256, 0, stream>>>(
        Sb, W2Tb, b2, x, Hb, BS, H, H);
    // --- out = LN(H)*gamma + beta ---
    ln_kernel<<<BS, 256, 0, stream>>>(Hb, gamma, beta, out);
}

// Round 4
// 264.481 us; speedup vs baseline: 3.9836x; 1.0807x over previous
//
#include <hip/hip_runtime.h>
#include <hip/hip_bf16.h>
#include <math.h>

// Problem dims: B=16,S=512,W=5,D=200,H=768  (BS=8192 rows, M1=40960 word-rows)
// Restructured math (softmax shift-invariance + linearity):
//   Ct = W2 @ attn_W^T                [768,768] bf16
//   T  = tanh(E @ W1 + b1)            [40960,768] bf16   (K padded 200->224)
//   P  = x @ C                        [8192,768] bf16    (logit_w = T_w . P)
//   alpha = softmax(logits + mask);  S = sum_w alpha_w T_w   [8192,768] bf16
//   H  = x + S @ W2 + b2              [8192,768] fp32
//   out = LayerNorm(H) * gamma + beta
// R4: fast tanh (hw exp+rcp, was libm tanhf = 5x the MFMA cycles -> MfmaUtil 10%),
//     constexpr N/K (immediate-offset epilogue addressing), K-pad 224 not 256.

typedef __attribute__((ext_vector_type(8))) short bf16x8;
typedef __attribute__((ext_vector_type(4))) float f32x4;

__device__ __forceinline__ unsigned short f2bf_bits(float f) {
    __hip_bfloat16 h = __float2bfloat16(f);
    return *reinterpret_cast<unsigned short*>(&h);
}
__device__ __forceinline__ float bf_bits2f(unsigned short u) {
    union { unsigned int i; float f; } v; v.i = ((unsigned int)u) << 16; return v.f;
}
__device__ __forceinline__ float tanh_fast(float x) {
    float xc = fminf(fmaxf(x, -9.f), 9.f);
    float t  = __expf(2.f * xc);                 // v_exp_f32 path
    return (t - 1.f) * __builtin_amdgcn_rcpf(t + 1.f);
}

// async 16B/lane global->LDS (wave-uniform chunk base + lane*16 layout)
__device__ __forceinline__ void async_cp16(const void* g, void* lds) {
#if __has_builtin(__builtin_amdgcn_global_load_lds)
    auto gp = (const __attribute__((address_space(1))) unsigned int*)g;
    auto lp = (__attribute__((address_space(3))) unsigned int*)lds;
    __builtin_amdgcn_global_load_lds(gp, lp, 16, 0, 0);
#else
    *(uint4*)lds = *(const uint4*)g;
#endif
}

// ---------- MFMA bf16 GEMM: D = A[M,K] @ Bt[N,K]^T (+bias)(tanh)(+resid) ----------
// M%128==0; N,K compile-time, K%32==0
template<bool HAS_BIAS, bool TANH_ACT, bool RESID, bool OUT_BF16, int N, int K>
__global__ __launch_bounds__(256) void mfma_gemm(
    const __hip_bfloat16* __restrict__ A,
    const __hip_bfloat16* __restrict__ Bt,
    const float* __restrict__ bias,
    const float* __restrict__ resid,
    void* __restrict__ outp)
{
    __shared__ __align__(16) unsigned short As[128 * 32];   // [row][k] 64B rows
    __shared__ __align__(16) unsigned short Bs[128 * 32];
    const int tid  = threadIdx.x;
    const int lane = tid & 63;
    const int wave = tid >> 6;          // 4 waves, 2x2
    const int wm   = wave & 1;
    const int wn   = wave >> 1;
    const int m0   = blockIdx.y * 128;
    const int n0   = blockIdx.x * 128;

    const int srow  = lane >> 2;         // 0..15
    const int skoff = (lane & 3) * 8;    // k elem offset 0/8/16/24
    const __hip_bfloat16* gA = A  + (size_t)(m0 + wave * 32 + srow) * K + skoff;
    const __hip_bfloat16* gB = Bt + (size_t)(n0 + wave * 32 + srow) * K + skoff;
    unsigned short* lA = &As[wave * 1024 + lane * 8];
    unsigned short* lB = &Bs[wave * 1024 + lane * 8];

    const int row16 = lane & 15;
    const int kq    = lane >> 4;         // 0..3

    f32x4 acc[4][4];
#pragma unroll
    for (int i = 0; i < 4; i++)
#pragma unroll
        for (int j = 0; j < 4; j++) acc[i][j] = (f32x4){0.f, 0.f, 0.f, 0.f};

    for (int k0 = 0; k0 < K; k0 += 32) {
        async_cp16(gA,          lA);
        async_cp16(gA + 16 * K, lA + 512);
        async_cp16(gB,          lB);
        async_cp16(gB + 16 * K, lB + 512);
        gA += 32; gB += 32;
        __syncthreads();                 // drains vmcnt before ds_read

        bf16x8 af[4], bg[4];
#pragma unroll
        for (int mi = 0; mi < 4; mi++)
            af[mi] = *(const bf16x8*)&As[(wm * 64 + mi * 16 + row16) * 32 + kq * 8];
#pragma unroll
        for (int ni = 0; ni < 4; ni++)
            bg[ni] = *(const bf16x8*)&Bs[(wn * 64 + ni * 16 + row16) * 32 + kq * 8];
#pragma unroll
        for (int mi = 0; mi < 4; mi++)
#pragma unroll
            for (int ni = 0; ni < 4; ni++)
                acc[mi][ni] = __builtin_amdgcn_mfma_f32_16x16x32_bf16(
                    af[mi], bg[ni], acc[mi][ni], 0, 0, 0);
        __syncthreads();
    }

    // epilogue: C/D layout col=lane&15, row=(lane>>4)*4+reg
#pragma unroll
    for (int ni = 0; ni < 4; ni++) {
        const int gcol = n0 + wn * 64 + ni * 16 + row16;
        float bcol = 0.f;
        if (HAS_BIAS) bcol = bias[gcol];
#pragma unroll
        for (int mi = 0; mi < 4; mi++) {
#pragma unroll
            for (int r = 0; r < 4; r++) {
                const int grow = m0 + wm * 64 + mi * 16 + kq * 4 + r;
                float v = acc[mi][ni][r];
                if (HAS_BIAS) v += bcol;
                if (TANH_ACT) v = tanh_fast(v);
                if (RESID)    v += resid[(size_t)grow * N + gcol];
                if (OUT_BF16) ((__hip_bfloat16*)outp)[(size_t)grow * N + gcol] = __float2bfloat16(v);
                else          ((float*)outp)[(size_t)grow * N + gcol] = v;
            }
        }
    }
}

// ---------- fused fp32->bf16 for x, W2, attn_W (one launch) ----------
__global__ __launch_bounds__(256) void cvt_all(
    const float* __restrict__ x,  __hip_bfloat16* __restrict__ xb,
    const float* __restrict__ w2, __hip_bfloat16* __restrict__ w2b,
    const float* __restrict__ aw, __hip_bfloat16* __restrict__ awb)
{
    const int NX = 8192 * 768 / 4;   // 1572864 -> 6144 blocks
    const int NW = 768 * 768 / 4;    //  147456 ->  576 blocks
    long long i = (long long)blockIdx.x * 256 + threadIdx.x;
    const float* src; __hip_bfloat16* dst;
    if (i < NX)           { src = x;  dst = xb;  }
    else if (i < NX + NW) { src = w2; dst = w2b; i -= NX; }
    else                  { src = aw; dst = awb; i -= NX + NW; if (i >= NW) return; }
    float4 v = ((const float4*)src)[i];
    ((ushort4*)dst)[i] = make_ushort4(f2bf_bits(v.x), f2bf_bits(v.y), f2bf_bits(v.z), f2bf_bits(v.w));
}

// ---------- E [40960,200] fp32 -> Eb [40960,224] bf16 (zero-padded K) ----------
__global__ __launch_bounds__(256) void cvt_padE(const float* __restrict__ E,
                                                __hip_bfloat16* __restrict__ Eb)
{
    const int row = blockIdx.x, k = threadIdx.x;
    if (k < 224) {
        float v = (k < 200) ? E[(size_t)row * 200 + k] : 0.f;
        Eb[(size_t)row * 224 + k] = __float2bfloat16(v);
    }
}

// ---------- transpose+cvt: in[R,C] fp32 -> out[C,Rpad] bf16 (rows R..Rpad zero) ----------
__global__ __launch_bounds__(256) void transpose_cvt(const float* __restrict__ in,
                                                     __hip_bfloat16* __restrict__ out,
                                                     int R, int C, int Rpad)
{
    __shared__ float tile[32][33];
    const int c0 = blockIdx.x * 32, r0 = blockIdx.y * 32;
    const int x = threadIdx.x, y = threadIdx.y;     // block (32,8)
#pragma unroll
    for (int i = 0; i < 32; i += 8) {
        int r = r0 + y + i;
        tile[y + i][x] = (r < R) ? in[(size_t)r * C + c0 + x] : 0.f;
    }
    __syncthreads();
#pragma unroll
    for (int i = 0; i < 32; i += 8)
        out[(size_t)(c0 + y + i) * Rpad + r0 + x] = __float2bfloat16(tile[x][y + i]);
}

// ---------- attention: wave per (b,s) row; P aliases S ----------
__global__ __launch_bounds__(256) void attn_kernel(
    const __hip_bfloat16* __restrict__ T,   // [40960,768]
    const __hip_bfloat16* P,                // [8192,768]
    const int* __restrict__ mask,           // [8192,5] int32
    __hip_bfloat16* S)                      // [8192,768]
{
    const int lane = threadIdx.x & 63;
    const int wave = threadIdx.x >> 6;
    const int r    = blockIdx.x * 4 + wave;
    const int base = lane * 12;             // 64*12 = 768

    float pv[12];
    {
        const ushort4* pp = (const ushort4*)((const unsigned short*)P + (size_t)r * 768 + base);
        ushort4 u0 = pp[0], u1 = pp[1], u2 = pp[2];
        unsigned short us[12] = {u0.x,u0.y,u0.z,u0.w, u1.x,u1.y,u1.z,u1.w, u2.x,u2.y,u2.z,u2.w};
#pragma unroll
        for (int j = 0; j < 12; j++) pv[j] = bf_bits2f(us[j]);
    }
    float tv[5][12], part[5];
#pragma unroll
    for (int w = 0; w < 5; w++) {
        const ushort4* tp = (const ushort4*)((const unsigned short*)T + ((size_t)r * 5 + w) * 768 + base);
        ushort4 u0 = tp[0], u1 = tp[1], u2 = tp[2];
        unsigned short us[12] = {u0.x,u0.y,u0.z,u0.w, u1.x,u1.y,u1.z,u1.w, u2.x,u2.y,u2.z,u2.w};
        float s = 0.f;
#pragma unroll
        for (int j = 0; j < 12; j++) { tv[w][j] = bf_bits2f(us[j]); s += tv[w][j] * pv[j]; }
        part[w] = s;
    }
#pragma unroll
    for (int off = 32; off > 0; off >>= 1)
#pragma unroll
        for (int w = 0; w < 5; w++)
            part[w] += __shfl_xor(part[w], off, 64);

    float logit[5], mx = -1e30f;
#pragma unroll
    for (int w = 0; w < 5; w++) {
        float m = (float)mask[(size_t)r * 5 + w];
        logit[w] = part[w] - 10000.0f * (1.0f - m);
        mx = fmaxf(mx, logit[w]);
    }
    float se = 0.f;
#pragma unroll
    for (int w = 0; w < 5; w++) { logit[w] = expf(logit[w] - mx); se += logit[w]; }
    const float inv = 1.0f / se;

    unsigned short os[12];
#pragma unroll
    for (int j = 0; j < 12; j++) {
        float s = 0.f;
#pragma unroll
        for (int w = 0; w < 5; w++) s += logit[w] * tv[w][j];
        os[j] = f2bf_bits(s * inv);
    }
    ushort4* sp = (ushort4*)((unsigned short*)S + (size_t)r * 768 + base);
    sp[0] = make_ushort4(os[0], os[1], os[2],  os[3]);
    sp[1] = make_ushort4(os[4], os[5], os[6],  os[7]);
    sp[2] = make_ushort4(os[8], os[9], os[10], os[11]);
}

// ---------- LayerNorm over H=768 ----------
__global__ __launch_bounds__(256) void ln_kernel(
    const float* __restrict__ Hbuf, const float* __restrict__ gamma,
    const float* __restrict__ beta, float* __restrict__ out)
{
    const int r = blockIdx.x, t = threadIdx.x;
    __shared__ float red[256];
    float v[3];
    float s = 0.f;
#pragma unroll
    for (int c = 0; c < 3; c++) { v[c] = Hbuf[(size_t)r * 768 + t + 256 * c]; s += v[c]; }
    red[t] = s; __syncthreads();
    for (int off = 128; off > 0; off >>= 1) { if (t < off) red[t] += red[t + off]; __syncthreads(); }
    const float mu = red[0] * (1.f / 768.f);
    __syncthreads();
    float vs = 0.f;
#pragma unroll
    for (int c = 0; c < 3; c++) { float d = v[c] - mu; vs += d * d; }
    red[t] = vs; __syncthreads();
    for (int off = 128; off > 0; off >>= 1) { if (t < off) red[t] += red[t + off]; __syncthreads(); }
    const float var = red[0] * (1.f / 768.f);
    const float rs = rsqrtf(var + 1e-12f);
#pragma unroll
    for (int c = 0; c < 3; c++) {
        int h = t + 256 * c;
        out[(size_t)r * 768 + h] = (v[c] - mu) * rs * gamma[h] + beta[h];
    }
}

extern "C" void kernel_launch(void* const* d_in, const int* in_sizes, int n_in,
                              void* d_out, int out_size, void* d_ws, size_t ws_size,
                              hipStream_t stream)
{
    const float* x      = (const float*)d_in[0];      // [8192,768]
    const float* E      = (const float*)d_in[1];      // [40960,200]
    const int*   mask   = (const int*)d_in[2];        // [8192,5] int32
    const float* W1     = (const float*)d_in[3];      // [200,768]
    const float* b1     = (const float*)d_in[4];      // [768]
    const float* W2     = (const float*)d_in[5];      // [768,768]
    const float* b2     = (const float*)d_in[6];      // [768]
    const float* attn_W = (const float*)d_in[7];      // [768,768]
    const float* gamma  = (const float*)d_in[8];      // [768]
    const float* beta   = (const float*)d_in[9];      // [768]
    float* out = (float*)d_out;

    const int BS = 8192, H = 768, M1 = 40960, KP = 224;

    char* p = (char*)d_ws;
    auto alloc = [&](size_t bytes) { char* q = p; p += (bytes + 255) & ~(size_t)255; return q; };
    __hip_bfloat16* xb    = (__hip_bfloat16*)alloc((size_t)BS * H * 2);   // 12.58 MB
    __hip_bfloat16* W2b   = (__hip_bfloat16*)alloc((size_t)H * H * 2);
    __hip_bfloat16* W2Tb  = (__hip_bfloat16*)alloc((size_t)H * H * 2);
    __hip_bfloat16* attnb = (__hip_bfloat16*)alloc((size_t)H * H * 2);
    __hip_bfloat16* Ctb   = (__hip_bfloat16*)alloc((size_t)H * H * 2);
    __hip_bfloat16* W1Tb  = (__hip_bfloat16*)alloc((size_t)H * KP * 2);
    __hip_bfloat16* Tb    = (__hip_bfloat16*)alloc((size_t)M1 * H * 2);  // 62.91 MB
    __hip_bfloat16* Eb    = (__hip_bfloat16*)alloc((size_t)M1 * KP * 2); // 18.35 MB
    float* Hb = (float*)Tb;              // alias: Tb dead after attn
    __hip_bfloat16* Pb = Eb;             // alias: Eb dead after T-GEMM
    __hip_bfloat16* Sb = Pb;             // alias: same-wave read-then-write

    // --- conversions ---
    cvt_all<<<6144 + 576 + 576, 256, 0, stream>>>(x, xb, W2, W2b, attn_W, attnb);
    cvt_padE<<<M1, 256, 0, stream>>>(E, Eb);
    transpose_cvt<<<dim3(24, 7),  dim3(32, 8), 0, stream>>>(W1, W1Tb, 200, H, KP);
    transpose_cvt<<<dim3(24, 24), dim3(32, 8), 0, stream>>>(W2, W2Tb, H, H, H);

    // --- Ct = W2 @ attn_W^T -> bf16 [768,768] ---
    mfma_gemm<false, false, false, true, 768, 768><<<dim3(6, 6), 256, 0, stream>>>(
        W2b, attnb, nullptr, nullptr, Ctb);
    // --- T = tanh(Eb @ W1 + b1) -> bf16 [40960,768], K=224 padded ---
    mfma_gemm<true, true, false, true, 768, 224><<<dim3(6, 320), 256, 0, stream>>>(
        Eb, W1Tb, b1, nullptr, Tb);
    // --- P = x @ C -> bf16 [8192,768] ---
    mfma_gemm<false, false, false, true, 768, 768><<<dim3(6, 64), 256, 0, stream>>>(
        xb, Ctb, nullptr, nullptr, Pb);
    // --- attention -> S bf16 ---
    attn_kernel<<<BS / 4, 256, 0, stream>>>(Tb, Pb, mask, Sb);
    // --- H = x + S @ W2 + b2 -> fp32 ---
    mfma_gemm<true, false, true, false, 768, 768><<<dim3(6, 64), 256, 0, stream>>>(
        Sb, W2Tb, b2, x, Hb);
    // --- out = LN(H)*gamma + beta ---
    ln_kernel<<<BS, 256, 0, stream>>>(Hb, gamma, beta, out);
}

// Round 6
// 242.061 us; speedup vs baseline: 4.3526x; 1.0926x over previous
//
#include <hip/hip_runtime.h>
#include <hip/hip_bf16.h>
#include <math.h>

// Problem dims: B=16,S=512,W=5,D=200,H=768  (BS=8192 rows, M1=40960 word-rows)
// Math (softmax shift-invariance + linearity):
//   Ct = W2 @ attn_W^T; T = tanh(E@W1+b1); P = x@C; alpha = softmax(T_w.P + mask)
//   S = sum_w alpha_w T_w; H = x + S@W2 + b2; out = LN(H)*gamma+beta
// R6: fix R5's bf16 epilogue store-loop index split (was lin>>3/&7 = 8 chunks/row
//     over 256 rows -> OOB rep reads + stomped neighbor tiles; correct is
//     lin>>4/&15 = 16 chunks/row over 128 rows). All else identical to R5.

typedef __attribute__((ext_vector_type(8))) short bf16x8;
typedef __attribute__((ext_vector_type(4))) float f32x4;

__device__ __forceinline__ unsigned short f2bf_bits(float f) {
    __hip_bfloat16 h = __float2bfloat16(f);
    return *reinterpret_cast<unsigned short*>(&h);
}
__device__ __forceinline__ float bf_bits2f(unsigned short u) {
    union { unsigned int i; float f; } v; v.i = ((unsigned int)u) << 16; return v.f;
}
__device__ __forceinline__ float tanh_fast(float x) {
    float xc = fminf(fmaxf(x, -9.f), 9.f);
    float t  = __expf(2.f * xc);
    return (t - 1.f) * __builtin_amdgcn_rcpf(t + 1.f);
}

__device__ __forceinline__ void async_cp16(const void* g, void* lds) {
#if __has_builtin(__builtin_amdgcn_global_load_lds)
    auto gp = (const __attribute__((address_space(1))) unsigned int*)g;
    auto lp = (__attribute__((address_space(3))) unsigned int*)lds;
    __builtin_amdgcn_global_load_lds(gp, lp, 16, 0, 0);
#else
    *(uint4*)lds = *(const uint4*)g;
#endif
}

// ---------- MFMA bf16 GEMM: D = A[M,K] @ Bt[N,K]^T (+bias)(tanh)(+resid) ----------
// 1D grid (= GX * gridY blocks); M%128==0; N,K compile-time; K%32==0
template<bool HAS_BIAS, bool TANH_ACT, bool RESID, bool OUT_BF16, int N, int K, int GX>
__global__ __launch_bounds__(256) void mfma_gemm(
    const __hip_bfloat16* __restrict__ A,
    const __hip_bfloat16* __restrict__ Bt,
    const float* __restrict__ bias,
    const float* __restrict__ resid,
    void* __restrict__ outp)
{
    __shared__ __align__(16) unsigned char smem[32768];
    unsigned short* As = (unsigned short*)smem;            // 128x32 bf16 = 8KB
    unsigned short* Bs = (unsigned short*)(smem + 8192);   // 8KB

    // XCD-aware decode: co-locate the GX blocks sharing an A row-tile on one XCD
    int bx, by;
    {
        const int total = gridDim.x;
        const int per_xcd = total >> 3;
        if ((total & 7) == 0 && (per_xcd % GX) == 0) {
            int xcd = blockIdx.x & 7, idx = blockIdx.x >> 3;
            int lin = xcd * per_xcd + idx;
            by = lin / GX; bx = lin % GX;
        } else { by = blockIdx.x / GX; bx = blockIdx.x % GX; }
    }
    const int m0 = by * 128;
    const int n0 = bx * 128;

    const int tid  = threadIdx.x;
    const int lane = tid & 63;
    const int wave = tid >> 6;          // 4 waves, 2x2
    const int wm   = wave & 1;
    const int wn   = wave >> 1;

    const int srow  = lane >> 2;
    const int skoff = (lane & 3) * 8;
    const __hip_bfloat16* gA = A  + (size_t)(m0 + wave * 32 + srow) * K + skoff;
    const __hip_bfloat16* gB = Bt + (size_t)(n0 + wave * 32 + srow) * K + skoff;
    unsigned short* lA = As + wave * 1024 + lane * 8;
    unsigned short* lB = Bs + wave * 1024 + lane * 8;

    const int row16 = lane & 15;
    const int kq    = lane >> 4;

    f32x4 acc[4][4];
#pragma unroll
    for (int i = 0; i < 4; i++)
#pragma unroll
        for (int j = 0; j < 4; j++) acc[i][j] = (f32x4){0.f, 0.f, 0.f, 0.f};

    for (int k0 = 0; k0 < K; k0 += 32) {
        async_cp16(gA,          lA);
        async_cp16(gA + 16 * K, lA + 512);
        async_cp16(gB,          lB);
        async_cp16(gB + 16 * K, lB + 512);
        gA += 32; gB += 32;
        __syncthreads();

        bf16x8 af[4], bg[4];
#pragma unroll
        for (int mi = 0; mi < 4; mi++)
            af[mi] = *(const bf16x8*)&As[(wm * 64 + mi * 16 + row16) * 32 + kq * 8];
#pragma unroll
        for (int ni = 0; ni < 4; ni++)
            bg[ni] = *(const bf16x8*)&Bs[(wn * 64 + ni * 16 + row16) * 32 + kq * 8];
#pragma unroll
        for (int mi = 0; mi < 4; mi++)
#pragma unroll
            for (int ni = 0; ni < 4; ni++)
                acc[mi][ni] = __builtin_amdgcn_mfma_f32_16x16x32_bf16(
                    af[mi], bg[ni], acc[mi][ni], 0, 0, 0);
        __syncthreads();
    }

    // ---- epilogue: repack C-tile through LDS, then coalesced 16B stores ----
    if (OUT_BF16) {
        unsigned short* rep = (unsigned short*)smem;   // 128x128 bf16 = 32KB
#pragma unroll
        for (int ni = 0; ni < 4; ni++) {
            const int c = wn * 64 + ni * 16 + row16;
            float bcol = HAS_BIAS ? bias[n0 + c] : 0.f;
#pragma unroll
            for (int mi = 0; mi < 4; mi++)
#pragma unroll
                for (int r = 0; r < 4; r++) {
                    const int rr = wm * 64 + mi * 16 + kq * 4 + r;
                    float v = acc[mi][ni][r];
                    if (HAS_BIAS) v += bcol;
                    if (TANH_ACT) v = tanh_fast(v);
                    rep[rr * 128 + c] = f2bf_bits(v);
                }
        }
        __syncthreads();
#pragma unroll
        for (int p = 0; p < 8; p++) {
            const int lin = p * 256 + tid;     // 0..2047: 128 rows x 16 chunks of 8
            const int row = lin >> 4;          // R6 FIX (was >>3)
            const int c8  = lin & 15;          // R6 FIX (was &7)
            uint4 d = *(const uint4*)&rep[row * 128 + c8 * 8];
            *(uint4*)((__hip_bfloat16*)outp + (size_t)(m0 + row) * N + n0 + c8 * 8) = d;
        }
    } else {
        float* rep = (float*)smem;             // 64x128 f32 = 32KB per half
#pragma unroll
        for (int h = 0; h < 2; h++) {
            if (wm == h) {
#pragma unroll
                for (int ni = 0; ni < 4; ni++) {
                    const int c = wn * 64 + ni * 16 + row16;
                    float bcol = HAS_BIAS ? bias[n0 + c] : 0.f;
#pragma unroll
                    for (int mi = 0; mi < 4; mi++)
#pragma unroll
                        for (int r = 0; r < 4; r++) {
                            const int rr = mi * 16 + kq * 4 + r;   // 0..63
                            float v = acc[mi][ni][r];
                            if (HAS_BIAS) v += bcol;
                            if (TANH_ACT) v = tanh_fast(v);
                            rep[rr * 128 + c] = v;
                        }
                }
            }
            __syncthreads();
#pragma unroll
            for (int p = 0; p < 8; p++) {
                const int lin = p * 256 + tid;   // 0..2047: 64 rows x 32 float4
                const int row = lin >> 5;
                const int c4  = lin & 31;
                float4 v = *(const float4*)&rep[row * 128 + c4 * 4];
                const int grow = m0 + h * 64 + row;
                if (RESID) {
                    float4 rv = *(const float4*)&resid[(size_t)grow * N + n0 + c4 * 4];
                    v.x += rv.x; v.y += rv.y; v.z += rv.z; v.w += rv.w;
                }
                *(float4*)((float*)outp + (size_t)grow * N + n0 + c4 * 4) = v;
            }
            __syncthreads();
        }
    }
}

// ---------- fused fp32->bf16 for x, W2, attn_W ----------
__global__ __launch_bounds__(256) void cvt_all(
    const float* __restrict__ x,  __hip_bfloat16* __restrict__ xb,
    const float* __restrict__ w2, __hip_bfloat16* __restrict__ w2b,
    const float* __restrict__ aw, __hip_bfloat16* __restrict__ awb)
{
    const int NX = 8192 * 768 / 4;
    const int NW = 768 * 768 / 4;
    long long i = (long long)blockIdx.x * 256 + threadIdx.x;
    const float* src; __hip_bfloat16* dst;
    if (i < NX)           { src = x;  dst = xb;  }
    else if (i < NX + NW) { src = w2; dst = w2b; i -= NX; }
    else                  { src = aw; dst = awb; i -= NX + NW; if (i >= NW) return; }
    float4 v = ((const float4*)src)[i];
    ((ushort4*)dst)[i] = make_ushort4(f2bf_bits(v.x), f2bf_bits(v.y), f2bf_bits(v.z), f2bf_bits(v.w));
}

// ---------- E [40960,200] fp32 -> Eb [40960,224] bf16, wave per row ----------
__global__ __launch_bounds__(256) void cvt_padE(const float* __restrict__ E,
                                                __hip_bfloat16* __restrict__ Eb)
{
    const int lane = threadIdx.x & 63;
    const int wave = threadIdx.x >> 6;
    const long long row = (long long)blockIdx.x * 4 + wave;
    const int k = lane * 4;
    if (k < 224) {
        float4 v = make_float4(0.f, 0.f, 0.f, 0.f);
        if (k < 200) v = *(const float4*)&E[row * 200 + k];    // k<=196 -> in-bounds
        *(ushort4*)&Eb[row * 224 + k] =
            make_ushort4(f2bf_bits(v.x), f2bf_bits(v.y), f2bf_bits(v.z), f2bf_bits(v.w));
    }
}

// ---------- transpose+cvt: in[R,C] fp32 -> out[C,Rpad] bf16 ----------
__global__ __launch_bounds__(256) void transpose_cvt(const float* __restrict__ in,
                                                     __hip_bfloat16* __restrict__ out,
                                                     int R, int C, int Rpad)
{
    __shared__ float tile[32][33];
    const int c0 = blockIdx.x * 32, r0 = blockIdx.y * 32;
    const int x = threadIdx.x, y = threadIdx.y;
#pragma unroll
    for (int i = 0; i < 32; i += 8) {
        int r = r0 + y + i;
        tile[y + i][x] = (r < R) ? in[(size_t)r * C + c0 + x] : 0.f;
    }
    __syncthreads();
#pragma unroll
    for (int i = 0; i < 32; i += 8)
        out[(size_t)(c0 + y + i) * Rpad + r0 + x] = __float2bfloat16(tile[x][y + i]);
}

// ---------- attention: wave per (b,s) row; P aliases S ----------
__global__ __launch_bounds__(256) void attn_kernel(
    const __hip_bfloat16* __restrict__ T,
    const __hip_bfloat16* P,
    const int* __restrict__ mask,
    __hip_bfloat16* S)
{
    const int lane = threadIdx.x & 63;
    const int wave = threadIdx.x >> 6;
    const int r    = blockIdx.x * 4 + wave;
    const int base = lane * 12;

    float pv[12];
    {
        const ushort4* pp = (const ushort4*)((const unsigned short*)P + (size_t)r * 768 + base);
        ushort4 u0 = pp[0], u1 = pp[1], u2 = pp[2];
        unsigned short us[12] = {u0.x,u0.y,u0.z,u0.w, u1.x,u1.y,u1.z,u1.w, u2.x,u2.y,u2.z,u2.w};
#pragma unroll
        for (int j = 0; j < 12; j++) pv[j] = bf_bits2f(us[j]);
    }
    float tv[5][12], part[5];
#pragma unroll
    for (int w = 0; w < 5; w++) {
        const ushort4* tp = (const ushort4*)((const unsigned short*)T + ((size_t)r * 5 + w) * 768 + base);
        ushort4 u0 = tp[0], u1 = tp[1], u2 = tp[2];
        unsigned short us[12] = {u0.x,u0.y,u0.z,u0.w, u1.x,u1.y,u1.z,u1.w, u2.x,u2.y,u2.z,u2.w};
        float s = 0.f;
#pragma unroll
        for (int j = 0; j < 12; j++) { tv[w][j] = bf_bits2f(us[j]); s += tv[w][j] * pv[j]; }
        part[w] = s;
    }
#pragma unroll
    for (int off = 32; off > 0; off >>= 1)
#pragma unroll
        for (int w = 0; w < 5; w++)
            part[w] += __shfl_xor(part[w], off, 64);

    float logit[5], mx = -1e30f;
#pragma unroll
    for (int w = 0; w < 5; w++) {
        float m = (float)mask[(size_t)r * 5 + w];
        logit[w] = part[w] - 10000.0f * (1.0f - m);
        mx = fmaxf(mx, logit[w]);
    }
    float se = 0.f;
#pragma unroll
    for (int w = 0; w < 5; w++) { logit[w] = expf(logit[w] - mx); se += logit[w]; }
    const float inv = 1.0f / se;

    unsigned short os[12];
#pragma unroll
    for (int j = 0; j < 12; j++) {
        float s = 0.f;
#pragma unroll
        for (int w = 0; w < 5; w++) s += logit[w] * tv[w][j];
        os[j] = f2bf_bits(s * inv);
    }
    ushort4* sp = (ushort4*)((unsigned short*)S + (size_t)r * 768 + base);
    sp[0] = make_ushort4(os[0], os[1], os[2],  os[3]);
    sp[1] = make_ushort4(os[4], os[5], os[6],  os[7]);
    sp[2] = make_ushort4(os[8], os[9], os[10], os[11]);
}

// ---------- LayerNorm over H=768, wave per row ----------
__global__ __launch_bounds__(256) void ln_kernel(
    const float* __restrict__ Hbuf, const float* __restrict__ gamma,
    const float* __restrict__ beta, float* __restrict__ out)
{
    const int lane = threadIdx.x & 63;
    const int wave = threadIdx.x >> 6;
    const int r    = blockIdx.x * 4 + wave;
    const float* hr = Hbuf + (size_t)r * 768 + lane * 12;

    float v[12];
    {
        float4 a = *(const float4*)(hr);
        float4 b = *(const float4*)(hr + 4);
        float4 c = *(const float4*)(hr + 8);
        v[0]=a.x; v[1]=a.y; v[2]=a.z; v[3]=a.w;
        v[4]=b.x; v[5]=b.y; v[6]=b.z; v[7]=b.w;
        v[8]=c.x; v[9]=c.y; v[10]=c.z; v[11]=c.w;
    }
    float s = 0.f;
#pragma unroll
    for (int j = 0; j < 12; j++) s += v[j];
#pragma unroll
    for (int off = 32; off > 0; off >>= 1) s += __shfl_xor(s, off, 64);
    const float mu = s * (1.f / 768.f);
    float vs = 0.f;
#pragma unroll
    for (int j = 0; j < 12; j++) { float d = v[j] - mu; vs += d * d; }
#pragma unroll
    for (int off = 32; off > 0; off >>= 1) vs += __shfl_xor(vs, off, 64);
    const float rs = rsqrtf(vs * (1.f / 768.f) + 1e-12f);

    float o[12];
#pragma unroll
    for (int j = 0; j < 12; j++) {
        int h = lane * 12 + j;
        o[j] = (v[j] - mu) * rs * gamma[h] + beta[h];
    }
    float* orow = out + (size_t)r * 768 + lane * 12;
    *(float4*)(orow)     = make_float4(o[0], o[1], o[2],  o[3]);
    *(float4*)(orow + 4) = make_float4(o[4], o[5], o[6],  o[7]);
    *(float4*)(orow + 8) = make_float4(o[8], o[9], o[10], o[11]);
}

extern "C" void kernel_launch(void* const* d_in, const int* in_sizes, int n_in,
                              void* d_out, int out_size, void* d_ws, size_t ws_size,
                              hipStream_t stream)
{
    const float* x      = (const float*)d_in[0];
    const float* E      = (const float*)d_in[1];
    const int*   mask   = (const int*)d_in[2];
    const float* W1     = (const float*)d_in[3];
    const float* b1     = (const float*)d_in[4];
    const float* W2     = (const float*)d_in[5];
    const float* b2     = (const float*)d_in[6];
    const float* attn_W = (const float*)d_in[7];
    const float* gamma  = (const float*)d_in[8];
    const float* beta   = (const float*)d_in[9];
    float* out = (float*)d_out;

    const int BS = 8192, H = 768, M1 = 40960, KP = 224;

    char* p = (char*)d_ws;
    auto alloc = [&](size_t bytes) { char* q = p; p += (bytes + 255) & ~(size_t)255; return q; };
    __hip_bfloat16* xb    = (__hip_bfloat16*)alloc((size_t)BS * H * 2);
    __hip_bfloat16* W2b   = (__hip_bfloat16*)alloc((size_t)H * H * 2);
    __hip_bfloat16* W2Tb  = (__hip_bfloat16*)alloc((size_t)H * H * 2);
    __hip_bfloat16* attnb = (__hip_bfloat16*)alloc((size_t)H * H * 2);
    __hip_bfloat16* Ctb   = (__hip_bfloat16*)alloc((size_t)H * H * 2);
    __hip_bfloat16* W1Tb  = (__hip_bfloat16*)alloc((size_t)H * KP * 2);
    __hip_bfloat16* Tb    = (__hip_bfloat16*)alloc((size_t)M1 * H * 2);
    __hip_bfloat16* Eb    = (__hip_bfloat16*)alloc((size_t)M1 * KP * 2);
    float* Hb = (float*)Tb;
    __hip_bfloat16* Pb = Eb;
    __hip_bfloat16* Sb = Pb;

    cvt_all<<<6144 + 576 + 576, 256, 0, stream>>>(x, xb, W2, W2b, attn_W, attnb);
    cvt_padE<<<M1 / 4, 256, 0, stream>>>(E, Eb);
    transpose_cvt<<<dim3(24, 7),  dim3(32, 8), 0, stream>>>(W1, W1Tb, 200, H, KP);
    transpose_cvt<<<dim3(24, 24), dim3(32, 8), 0, stream>>>(W2, W2Tb, H, H, H);

    // Ct = W2 @ attn_W^T   (36 blocks -> identity decode path)
    mfma_gemm<false, false, false, true, 768, 768, 6><<<36, 256, 0, stream>>>(
        W2b, attnb, nullptr, nullptr, Ctb);
    // T = tanh(Eb @ W1 + b1)   (1920 blocks, XCD-swizzled)
    mfma_gemm<true, true, false, true, 768, 224, 6><<<1920, 256, 0, stream>>>(
        Eb, W1Tb, b1, nullptr, Tb);
    // P = x @ C   (384 blocks, XCD-swizzled)
    mfma_gemm<false, false, false, true, 768, 768, 6><<<384, 256, 0, stream>>>(
        xb, Ctb, nullptr, nullptr, Pb);
    // attention -> S
    attn_kernel<<<BS / 4, 256, 0, stream>>>(Tb, Pb, mask, Sb);
    // H = x + S @ W2 + b2
    mfma_gemm<true, false, true, false, 768, 768, 6><<<384, 256, 0, stream>>>(
        Sb, W2Tb, b2, x, Hb);
    // out = LN(H)*gamma + beta
    ln_kernel<<<BS / 4, 256, 0, stream>>>(Hb, gamma, beta, out);
}

// Round 7
// 234.009 us; speedup vs baseline: 4.5024x; 1.0344x over previous
//
#include <hip/hip_runtime.h>
#include <hip/hip_bf16.h>
#include <math.h>

// Problem dims: B=16,S=512,W=5,D=200,H=768  (BS=8192 rows, M1=40960 word-rows)
// Math: Ct = W2@attn_W^T; T = tanh(E@W1+b1); P = x@C; alpha = softmax(T_w.P+mask)
//       S = sum_w alpha_w T_w; H = x + S@W2 + b2; out = LN(H)*gamma+beta
// R7: (a) BK=64 K-loop (32 MFMA per wave per barrier-pair, was 16) with
//     XOR-swizzled LDS (slot = kc ^ (row&7)) -- the old 64B-row layout had an
//     8-way bank conflict on every ds_read_b128 quad (SQ_LDS_BANK_CONFLICT
//     ~1.8e6/dispatch in R3/R4); swizzle permutes global src addrs across
//     lanes so global_load_lds's base+lane*16 dest constraint still holds.
//     (b) K-pad 256 (BK=64 divisibility). (c) all prep fused into one kernel.

typedef __attribute__((ext_vector_type(8))) short bf16x8;
typedef __attribute__((ext_vector_type(4))) float f32x4;

__device__ __forceinline__ unsigned short f2bf_bits(float f) {
    __hip_bfloat16 h = __float2bfloat16(f);
    return *reinterpret_cast<unsigned short*>(&h);
}
__device__ __forceinline__ float bf_bits2f(unsigned short u) {
    union { unsigned int i; float f; } v; v.i = ((unsigned int)u) << 16; return v.f;
}
__device__ __forceinline__ float tanh_fast(float x) {
    float xc = fminf(fmaxf(x, -9.f), 9.f);
    float t  = __expf(2.f * xc);
    return (t - 1.f) * __builtin_amdgcn_rcpf(t + 1.f);
}

__device__ __forceinline__ void async_cp16(const void* g, void* lds) {
#if __has_builtin(__builtin_amdgcn_global_load_lds)
    auto gp = (const __attribute__((address_space(1))) unsigned int*)g;
    auto lp = (__attribute__((address_space(3))) unsigned int*)lds;
    __builtin_amdgcn_global_load_lds(gp, lp, 16, 0, 0);
#else
    *(uint4*)lds = *(const uint4*)g;
#endif
}

// ---------- MFMA bf16 GEMM: D = A[M,K] @ Bt[N,K]^T (+bias)(tanh)(+resid) ----------
// 1D grid (GX * gridY blocks); M%128==0; N,K compile-time; K%64==0
template<bool HAS_BIAS, bool TANH_ACT, bool RESID, bool OUT_BF16, int N, int K, int GX>
__global__ __launch_bounds__(256) void mfma_gemm(
    const __hip_bfloat16* __restrict__ A,
    const __hip_bfloat16* __restrict__ Bt,
    const float* __restrict__ bias,
    const float* __restrict__ resid,
    void* __restrict__ outp)
{
    __shared__ __align__(16) unsigned char smem[32768];
    unsigned short* As = (unsigned short*)smem;            // 128 rows x 64 k = 16KB
    unsigned short* Bs = (unsigned short*)(smem + 16384);  // 16KB

    // XCD-aware decode: co-locate the GX blocks sharing an A row-tile on one XCD
    int bx, by;
    {
        const int total = gridDim.x;
        const int per_xcd = total >> 3;
        if ((total & 7) == 0 && (per_xcd % GX) == 0) {
            int xcd = blockIdx.x & 7, idx = blockIdx.x >> 3;
            int lin = xcd * per_xcd + idx;
            by = lin / GX; bx = lin % GX;
        } else { by = blockIdx.x / GX; bx = blockIdx.x % GX; }
    }
    const int m0 = by * 128;
    const int n0 = bx * 128;

    const int tid  = threadIdx.x;
    const int lane = tid & 63;
    const int wave = tid >> 6;          // 4 waves, 2x2
    const int wm   = wave & 1;
    const int wn   = wave >> 1;

    // staging: wave covers rows [wave*32, wave*32+32); issue i covers 8 rows.
    // XOR swizzle: chunk (r, kc) lives at slot s = kc ^ (r&7); we permute the
    // GLOBAL source per lane (kc = slot ^ rsub) so LDS dest stays base+lane*16.
    const int rsub = lane >> 3;          // 0..7
    const int slot = lane & 7;           // 0..7
    const int kc   = slot ^ rsub;        // logical k-chunk this lane fetches
    const __hip_bfloat16* gA = A  + (size_t)(m0 + wave * 32 + rsub) * K + kc * 8;
    const __hip_bfloat16* gB = Bt + (size_t)(n0 + wave * 32 + rsub) * K + kc * 8;
    unsigned short* lA = As + wave * 2048 + lane * 8;
    unsigned short* lB = Bs + wave * 2048 + lane * 8;

    const int row16 = lane & 15;
    const int kq    = lane >> 4;         // 0..3

    f32x4 acc[4][4];
#pragma unroll
    for (int i = 0; i < 4; i++)
#pragma unroll
        for (int j = 0; j < 4; j++) acc[i][j] = (f32x4){0.f, 0.f, 0.f, 0.f};

    for (int k0 = 0; k0 < K; k0 += 64) {
#pragma unroll
        for (int i = 0; i < 4; i++) {
            async_cp16(gA + i * 8 * K, lA + i * 512);
            async_cp16(gB + i * 8 * K, lB + i * 512);
        }
        gA += 64; gB += 64;
        __syncthreads();

        bf16x8 af[2][4], bg[2][4];
#pragma unroll
        for (int kh = 0; kh < 2; kh++) {
#pragma unroll
            for (int mi = 0; mi < 4; mi++) {
                const int r = wm * 64 + mi * 16 + row16;
                const int s = (kh * 4 + kq) ^ (r & 7);
                af[kh][mi] = *(const bf16x8*)&As[r * 64 + s * 8];
            }
#pragma unroll
            for (int ni = 0; ni < 4; ni++) {
                const int r = wn * 64 + ni * 16 + row16;
                const int s = (kh * 4 + kq) ^ (r & 7);
                bg[kh][ni] = *(const bf16x8*)&Bs[r * 64 + s * 8];
            }
        }
#pragma unroll
        for (int kh = 0; kh < 2; kh++)
#pragma unroll
            for (int mi = 0; mi < 4; mi++)
#pragma unroll
                for (int ni = 0; ni < 4; ni++)
                    acc[mi][ni] = __builtin_amdgcn_mfma_f32_16x16x32_bf16(
                        af[kh][mi], bg[kh][ni], acc[mi][ni], 0, 0, 0);
        __syncthreads();
    }

    // ---- epilogue: repack C-tile through LDS, coalesced 16B stores ----
    if (OUT_BF16) {
        unsigned short* rep = (unsigned short*)smem;   // 128x128 bf16 = 32KB
#pragma unroll
        for (int ni = 0; ni < 4; ni++) {
            const int c = wn * 64 + ni * 16 + row16;
            float bcol = HAS_BIAS ? bias[n0 + c] : 0.f;
#pragma unroll
            for (int mi = 0; mi < 4; mi++)
#pragma unroll
                for (int r = 0; r < 4; r++) {
                    const int rr = wm * 64 + mi * 16 + kq * 4 + r;
                    float v = acc[mi][ni][r];
                    if (HAS_BIAS) v += bcol;
                    if (TANH_ACT) v = tanh_fast(v);
                    rep[rr * 128 + c] = f2bf_bits(v);
                }
        }
        __syncthreads();
#pragma unroll
        for (int p = 0; p < 8; p++) {
            const int lin = p * 256 + tid;     // 128 rows x 16 chunks of 8
            const int row = lin >> 4;
            const int c8  = lin & 15;
            uint4 d = *(const uint4*)&rep[row * 128 + c8 * 8];
            *(uint4*)((__hip_bfloat16*)outp + (size_t)(m0 + row) * N + n0 + c8 * 8) = d;
        }
    } else {
        float* rep = (float*)smem;             // 64x128 f32 = 32KB per half
#pragma unroll
        for (int h = 0; h < 2; h++) {
            if (wm == h) {
#pragma unroll
                for (int ni = 0; ni < 4; ni++) {
                    const int c = wn * 64 + ni * 16 + row16;
                    float bcol = HAS_BIAS ? bias[n0 + c] : 0.f;
#pragma unroll
                    for (int mi = 0; mi < 4; mi++)
#pragma unroll
                        for (int r = 0; r < 4; r++) {
                            const int rr = mi * 16 + kq * 4 + r;   // 0..63
                            float v = acc[mi][ni][r];
                            if (HAS_BIAS) v += bcol;
                            if (TANH_ACT) v = tanh_fast(v);
                            rep[rr * 128 + c] = v;
                        }
                }
            }
            __syncthreads();
#pragma unroll
            for (int p = 0; p < 8; p++) {
                const int lin = p * 256 + tid;   // 64 rows x 32 float4
                const int row = lin >> 5;
                const int c4  = lin & 31;
                float4 v = *(const float4*)&rep[row * 128 + c4 * 4];
                const int grow = m0 + h * 64 + row;
                if (RESID) {
                    float4 rv = *(const float4*)&resid[(size_t)grow * N + n0 + c4 * 4];
                    v.x += rv.x; v.y += rv.y; v.z += rv.z; v.w += rv.w;
                }
                *(float4*)((float*)outp + (size_t)grow * N + n0 + c4 * 4) = v;
            }
            __syncthreads();
        }
    }
}

// ---------- fused prep: cvt x/W2/attn_W, pad-cvt E (K->256), transpose W1/W2 ----------
__global__ __launch_bounds__(256) void prep_kernel(
    const float* __restrict__ x,  __hip_bfloat16* __restrict__ xb,
    const float* __restrict__ w2, __hip_bfloat16* __restrict__ w2b,
    const float* __restrict__ aw, __hip_bfloat16* __restrict__ awb,
    const float* __restrict__ E,  __hip_bfloat16* __restrict__ Eb,
    const float* __restrict__ W1, __hip_bfloat16* __restrict__ W1Tb,
    __hip_bfloat16* __restrict__ W2Tb)
{
    __shared__ float tile[32][33];
    const int b = blockIdx.x, tid = threadIdx.x;
    if (b < 6144 + 576 + 576) {                       // flat fp32->bf16 cvt
        const float* src; __hip_bfloat16* dst; long long i;
        if (b < 6144)      { src = x;  dst = xb;  i = (long long)b * 256 + tid; }
        else if (b < 6720) { src = w2; dst = w2b; i = (long long)(b - 6144) * 256 + tid; }
        else               { src = aw; dst = awb; i = (long long)(b - 6720) * 256 + tid; }
        float4 v = ((const float4*)src)[i];
        ((ushort4*)dst)[i] = make_ushort4(f2bf_bits(v.x), f2bf_bits(v.y), f2bf_bits(v.z), f2bf_bits(v.w));
    } else if (b < 7296 + 10240) {                    // E [40960,200] -> [40960,256]
        const int lane = tid & 63, wave = tid >> 6;
        const long long row = (long long)(b - 7296) * 4 + wave;
        const int k = lane * 4;
        float4 v = make_float4(0.f, 0.f, 0.f, 0.f);
        if (k < 200) v = *(const float4*)&E[row * 200 + k];   // k<=196 in-bounds
        *(ushort4*)&Eb[row * 256 + k] =
            make_ushort4(f2bf_bits(v.x), f2bf_bits(v.y), f2bf_bits(v.z), f2bf_bits(v.w));
    } else {                                          // transposes, (32,8) tiles
        const float* in; __hip_bfloat16* outb; int R, C, Rpad, t;
        if (b < 17536 + 192) { t = b - 17536; in = W1; outb = W1Tb; R = 200; C = 768; Rpad = 256; }
        else                 { t = b - 17728; in = w2; outb = W2Tb; R = 768; C = 768; Rpad = 768; }
        const int c0 = (t % 24) * 32, r0 = (t / 24) * 32;
        const int xx = tid & 31, yy = tid >> 5;       // (32,8)
#pragma unroll
        for (int i = 0; i < 32; i += 8) {
            int r = r0 + yy + i;
            tile[yy + i][xx] = (r < R) ? in[(size_t)r * C + c0 + xx] : 0.f;
        }
        __syncthreads();
#pragma unroll
        for (int i = 0; i < 32; i += 8)
            outb[(size_t)(c0 + yy + i) * Rpad + r0 + xx] = __float2bfloat16(tile[xx][yy + i]);
    }
}

// ---------- attention: wave per (b,s) row; P aliases S ----------
__global__ __launch_bounds__(256) void attn_kernel(
    const __hip_bfloat16* __restrict__ T,
    const __hip_bfloat16* P,
    const int* __restrict__ mask,
    __hip_bfloat16* S)
{
    const int lane = threadIdx.x & 63;
    const int wave = threadIdx.x >> 6;
    const int r    = blockIdx.x * 4 + wave;
    const int base = lane * 12;

    float pv[12];
    {
        const ushort4* pp = (const ushort4*)((const unsigned short*)P + (size_t)r * 768 + base);
        ushort4 u0 = pp[0], u1 = pp[1], u2 = pp[2];
        unsigned short us[12] = {u0.x,u0.y,u0.z,u0.w, u1.x,u1.y,u1.z,u1.w, u2.x,u2.y,u2.z,u2.w};
#pragma unroll
        for (int j = 0; j < 12; j++) pv[j] = bf_bits2f(us[j]);
    }
    float tv[5][12], part[5];
#pragma unroll
    for (int w = 0; w < 5; w++) {
        const ushort4* tp = (const ushort4*)((const unsigned short*)T + ((size_t)r * 5 + w) * 768 + base);
        ushort4 u0 = tp[0], u1 = tp[1], u2 = tp[2];
        unsigned short us[12] = {u0.x,u0.y,u0.z,u0.w, u1.x,u1.y,u1.z,u1.w, u2.x,u2.y,u2.z,u2.w};
        float s = 0.f;
#pragma unroll
        for (int j = 0; j < 12; j++) { tv[w][j] = bf_bits2f(us[j]); s += tv[w][j] * pv[j]; }
        part[w] = s;
    }
#pragma unroll
    for (int off = 32; off > 0; off >>= 1)
#pragma unroll
        for (int w = 0; w < 5; w++)
            part[w] += __shfl_xor(part[w], off, 64);

    float logit[5], mx = -1e30f;
#pragma unroll
    for (int w = 0; w < 5; w++) {
        float m = (float)mask[(size_t)r * 5 + w];
        logit[w] = part[w] - 10000.0f * (1.0f - m);
        mx = fmaxf(mx, logit[w]);
    }
    float se = 0.f;
#pragma unroll
    for (int w = 0; w < 5; w++) { logit[w] = expf(logit[w] - mx); se += logit[w]; }
    const float inv = 1.0f / se;

    unsigned short os[12];
#pragma unroll
    for (int j = 0; j < 12; j++) {
        float s = 0.f;
#pragma unroll
        for (int w = 0; w < 5; w++) s += logit[w] * tv[w][j];
        os[j] = f2bf_bits(s * inv);
    }
    ushort4* sp = (ushort4*)((unsigned short*)S + (size_t)r * 768 + base);
    sp[0] = make_ushort4(os[0], os[1], os[2],  os[3]);
    sp[1] = make_ushort4(os[4], os[5], os[6],  os[7]);
    sp[2] = make_ushort4(os[8], os[9], os[10], os[11]);
}

// ---------- LayerNorm over H=768, wave per row ----------
__global__ __launch_bounds__(256) void ln_kernel(
    const float* __restrict__ Hbuf, const float* __restrict__ gamma,
    const float* __restrict__ beta, float* __restrict__ out)
{
    const int lane = threadIdx.x & 63;
    const int wave = threadIdx.x >> 6;
    const int r    = blockIdx.x * 4 + wave;
    const float* hr = Hbuf + (size_t)r * 768 + lane * 12;

    float v[12];
    {
        float4 a = *(const float4*)(hr);
        float4 b = *(const float4*)(hr + 4);
        float4 c = *(const float4*)(hr + 8);
        v[0]=a.x; v[1]=a.y; v[2]=a.z; v[3]=a.w;
        v[4]=b.x; v[5]=b.y; v[6]=b.z; v[7]=b.w;
        v[8]=c.x; v[9]=c.y; v[10]=c.z; v[11]=c.w;
    }
    float s = 0.f;
#pragma unroll
    for (int j = 0; j < 12; j++) s += v[j];
#pragma unroll
    for (int off = 32; off > 0; off >>= 1) s += __shfl_xor(s, off, 64);
    const float mu = s * (1.f / 768.f);
    float vs = 0.f;
#pragma unroll
    for (int j = 0; j < 12; j++) { float d = v[j] - mu; vs += d * d; }
#pragma unroll
    for (int off = 32; off > 0; off >>= 1) vs += __shfl_xor(vs, off, 64);
    const float rs = rsqrtf(vs * (1.f / 768.f) + 1e-12f);

    float o[12];
#pragma unroll
    for (int j = 0; j < 12; j++) {
        int h = lane * 12 + j;
        o[j] = (v[j] - mu) * rs * gamma[h] + beta[h];
    }
    float* orow = out + (size_t)r * 768 + lane * 12;
    *(float4*)(orow)     = make_float4(o[0], o[1], o[2],  o[3]);
    *(float4*)(orow + 4) = make_float4(o[4], o[5], o[6],  o[7]);
    *(float4*)(orow + 8) = make_float4(o[8], o[9], o[10], o[11]);
}

extern "C" void kernel_launch(void* const* d_in, const int* in_sizes, int n_in,
                              void* d_out, int out_size, void* d_ws, size_t ws_size,
                              hipStream_t stream)
{
    const float* x      = (const float*)d_in[0];
    const float* E      = (const float*)d_in[1];
    const int*   mask   = (const int*)d_in[2];
    const float* W1     = (const float*)d_in[3];
    const float* b1     = (const float*)d_in[4];
    const float* W2     = (const float*)d_in[5];
    const float* b2     = (const float*)d_in[6];
    const float* attn_W = (const float*)d_in[7];
    const float* gamma  = (const float*)d_in[8];
    const float* beta   = (const float*)d_in[9];
    float* out = (float*)d_out;

    const int BS = 8192, H = 768, M1 = 40960, KP = 256;

    char* p = (char*)d_ws;
    auto alloc = [&](size_t bytes) { char* q = p; p += (bytes + 255) & ~(size_t)255; return q; };
    __hip_bfloat16* xb    = (__hip_bfloat16*)alloc((size_t)BS * H * 2);    // 12.58 MB
    __hip_bfloat16* W2b   = (__hip_bfloat16*)alloc((size_t)H * H * 2);
    __hip_bfloat16* W2Tb  = (__hip_bfloat16*)alloc((size_t)H * H * 2);
    __hip_bfloat16* attnb = (__hip_bfloat16*)alloc((size_t)H * H * 2);
    __hip_bfloat16* Ctb   = (__hip_bfloat16*)alloc((size_t)H * H * 2);
    __hip_bfloat16* W1Tb  = (__hip_bfloat16*)alloc((size_t)H * KP * 2);
    __hip_bfloat16* Tb    = (__hip_bfloat16*)alloc((size_t)M1 * H * 2);    // 62.92 MB
    __hip_bfloat16* Eb    = (__hip_bfloat16*)alloc((size_t)M1 * KP * 2);   // 20.97 MB
    float* Hb = (float*)Tb;              // alias: Tb dead after attn
    __hip_bfloat16* Pb = Eb;             // alias: Eb dead after T-GEMM
    __hip_bfloat16* Sb = Pb;             // alias: same-wave read-then-write

    // --- all prep in one launch: 6144+576+576 cvt, 10240 padE, 192+576 transpose
    prep_kernel<<<18304, 256, 0, stream>>>(x, xb, W2, W2b, attn_W, attnb,
                                           E, Eb, W1, W1Tb, W2Tb);

    // Ct = W2 @ attn_W^T   (36 blocks -> identity decode path)
    mfma_gemm<false, false, false, true, 768, 768, 6><<<36, 256, 0, stream>>>(
        W2b, attnb, nullptr, nullptr, Ctb);
    // T = tanh(Eb @ W1 + b1)   (1920 blocks, XCD-swizzled), K=256 padded
    mfma_gemm<true, true, false, true, 768, 256, 6><<<1920, 256, 0, stream>>>(
        Eb, W1Tb, b1, nullptr, Tb);
    // P = x @ C   (384 blocks, XCD-swizzled)
    mfma_gemm<false, false, false, true, 768, 768, 6><<<384, 256, 0, stream>>>(
        xb, Ctb, nullptr, nullptr, Pb);
    // attention -> S
    attn_kernel<<<BS / 4, 256, 0, stream>>>(Tb, Pb, mask, Sb);
    // H = x + S @ W2 + b2
    mfma_gemm<true, false, true, false, 768, 768, 6><<<384, 256, 0, stream>>>(
        Sb, W2Tb, b2, x, Hb);
    // out = LN(H)*gamma + beta
    ln_kernel<<<BS / 4, 256, 0, stream>>>(Hb, gamma, beta, out);
}